// Round 8
// baseline (524.052 us; speedup 1.0000x reference)
//
#include <hip/hip_runtime.h>
#include <cstddef>
#include <cstdint>
#include <cmath>

// Problem constants
#define BDIM  64
#define SDIM  1024
#define DDIM  200
#define DPAD  224            // 7 x 32 k-steps, 14 x 16 n-tiles
#define PSTRIDE 232          // global row stride of p_bf (== LDS K stride, bank-friendly)
#define CDIM  31
#define NSTACK 2
#define EPS   1e-5f
#define LN_N  204800.0f      // 1024*200 elements per batch LN plane

typedef __attribute__((ext_vector_type(8))) short short8;
typedef __attribute__((ext_vector_type(4))) short short4_t;
typedef __attribute__((ext_vector_type(4))) float f32x4;

__device__ __forceinline__ short f2bf(float f) {
    union { float f; unsigned u; } v; v.f = f;
    unsigned r = v.u + 0x7FFFu + ((v.u >> 16) & 1u);   // RNE
    return (short)(r >> 16);
}
__device__ __forceinline__ float bf2f(short s) {
    union { unsigned u; float f; } v; v.u = ((unsigned)(unsigned short)s) << 16;
    return v.f;
}
__device__ __forceinline__ unsigned cvtpk_bf16(float a, float b) {
    unsigned r;
    asm volatile("v_cvt_pk_bf16_f32 %0, %1, %2" : "=v"(r) : "v"(a), "v"(b));
    return r;
}
__device__ __forceinline__ void gload_lds16(const short* g, short* l) {
    __builtin_amdgcn_global_load_lds(
        (const __attribute__((address_space(1))) void*)g,
        (__attribute__((address_space(3))) void*)l, 16, 0, 0);
}

// ---------------- prep: padded bf16 transposed weights, biases, colsums --------
__global__ void prep_kernel(const float* __restrict__ Wp, const float* __restrict__ bp,
                            const float* __restrict__ Wm, const float* __restrict__ bm,
                            const float* __restrict__ W1, const float* __restrict__ b1,
                            const float* __restrict__ W2, const float* __restrict__ b2,
                            short* __restrict__ WtP, short* __restrict__ WtM,
                            short* __restrict__ Wt1, short* __restrict__ Wt2,
                            float* __restrict__ bpP, float* __restrict__ bmP,
                            float* __restrict__ b1P, float* __restrict__ b2P,
                            float* __restrict__ csP, float* __restrict__ cs1)
{
    int idx = blockIdx.x * 256 + threadIdx.x;
    if (idx >= DPAD * DPAD) return;
    int n = idx / DPAD, k = idx - n * DPAD;
    bool valid = (n < DDIM) && (k < DDIM);
    WtP[idx] = valid ? f2bf(Wp[(size_t)k * DDIM + n]) : 0;
    Wt1[idx] = valid ? f2bf(W1[(size_t)k * DDIM + n]) : 0;
    Wt2[idx] = valid ? f2bf(W2[(size_t)k * DDIM + n]) : 0;
    float s = 0.f;
    if (valid) {
        #pragma unroll
        for (int blk = 0; blk < 8; ++blk)
            s += Wm[(size_t)(blk * DDIM + k) * DDIM + n];
    }
    WtM[idx] = valid ? f2bf(s) : 0;
    if (idx < DPAD) {
        bpP[idx] = idx < DDIM ? bp[idx] : 0.f;
        bmP[idx] = idx < DDIM ? bm[idx] : 0.f;
        b1P[idx] = idx < DDIM ? b1[idx] : 0.f;
        b2P[idx] = idx < DDIM ? b2[idx] : 0.f;
        float sp = 0.f, s1 = 0.f;
        if (idx < DDIM) {
            for (int kk = 0; kk < DDIM; ++kk) {
                sp += bf2f(f2bf(Wp[(size_t)kk * DDIM + idx]));
                s1 += bf2f(f2bf(W1[(size_t)kk * DDIM + idx]));
            }
        }
        csP[idx] = sp;
        cs1[idx] = s1;
    }
}

// ---------------- h_bf = bf16(embed[x] + pos), zero-padded to 224 ----------------
__global__ void embed_kernel(const int* __restrict__ x, const float* __restrict__ embed,
                             const float* __restrict__ pos, short* __restrict__ h)
{
    const int total = BDIM * SDIM * (DPAD / 4);
    for (int i = blockIdx.x * 256 + threadIdx.x; i < total; i += gridDim.x * 256) {
        const int row = i / (DPAD / 4);
        const int n0  = (i - row * (DPAD / 4)) * 4;
        short4_t o;
        if (n0 >= DDIM) {
            o[0] = o[1] = o[2] = o[3] = 0;
        } else {
            const int s = row & (SDIM - 1);
            const int tok = x[row];
            const float4 e  = *(const float4*)(embed + (size_t)tok * DDIM + n0);
            const float4 p4 = *(const float4*)(pos + (size_t)s * DDIM + n0);
            o[0] = f2bf(e.x + p4.x); o[1] = f2bf(e.y + p4.y);
            o[2] = f2bf(e.z + p4.z); o[3] = f2bf(e.w + p4.w);
        }
        *(short4_t*)(h + (size_t)row * DPAD + n0) = o;
    }
}

// ---------------- bf16 MFMA GEMM, LDS-staged, coalesced LDS epilogue ----------
// out[M,224] = LN?(act) @ Wt^T + bias (+ LN?(res)) (+relu) (+stats)
// Main loop: A=act rows, B=Wt rows (C row=m(hi,r), col=n(lo)).
// Epilogue: raw acc -> LDS [128][236] bf16 -> coalesced half-row pass applies
// LN/bias/res/relu/stats with short8 loads/stores.
#define WSLICE 7168   // 224*32 shorts
#define GBUFSZ 11264  // WSLICE + 128*32
#define SSTRIDE 236
__global__ __launch_bounds__(256, 2)
void gemm_bf(const short* __restrict__ act, const float* __restrict__ actParts,
             const short* __restrict__ Wt, const float* __restrict__ bias,
             const float* __restrict__ csW,
             const short* __restrict__ res, const float* __restrict__ resParts,
             short* __restrict__ out, float* __restrict__ parts,
             int doRelu, int outStride)
{
    __shared__ short MEM[128 * SSTRIDE];   // 60416 B; staging dbuf carved from front

    const int tid  = threadIdx.x;
    const int wave = tid >> 6, lane = tid & 63;
    const int lo   = lane & 15, hi = lane >> 4;
    const int mblk = blockIdx.x * 128;

    auto stage = [&](int ks, int buf) {
        short* base = buf ? (MEM + GBUFSZ) : MEM;
        for (int c = wave; c < 22; c += 4) {
            if (c < 14) {
                int row = c * 16 + (lane >> 2);
                int kc  = (lane & 3) ^ ((row >> 1) & 3);
                gload_lds16(Wt + (size_t)row * DPAD + ks * 32 + kc * 8,
                            base + c * 512 + lane * 8);
            } else {
                int ci  = c - 14;
                int row = ci * 16 + (lane >> 2);
                int kc  = (lane & 3) ^ ((row >> 1) & 3);
                gload_lds16(act + (size_t)(mblk + row) * DPAD + ks * 32 + kc * 8,
                            base + WSLICE + ci * 512 + lane * 8);
            }
        }
    };

    f32x4 acc[2][14];
    #pragma unroll
    for (int mt = 0; mt < 2; ++mt)
        #pragma unroll
        for (int nt = 0; nt < 14; ++nt) acc[mt][nt] = (f32x4){0.f, 0.f, 0.f, 0.f};

    stage(0, 0);
    __syncthreads();

    #pragma unroll
    for (int ks = 0; ks < 7; ++ks) {
        const int cur = ks & 1;
        if (ks < 6) stage(ks + 1, cur ^ 1);
        const short* B_ = cur ? (MEM + GBUFSZ) : MEM;

        short8 af[2];
        #pragma unroll
        for (int mt = 0; mt < 2; ++mt) {
            int arow = wave * 32 + mt * 16 + lo;
            af[mt] = *(const short8*)&B_[WSLICE + arow * 32
                                         + ((hi * 8) ^ (((arow >> 1) & 3) << 3))];
        }
        #pragma unroll
        for (int nt = 0; nt < 14; ++nt) {
            int brow = nt * 16 + lo;
            short8 bf_ = *(const short8*)&B_[brow * 32
                                             + ((hi * 8) ^ (((brow >> 1) & 3) << 3))];
            acc[0][nt] = __builtin_amdgcn_mfma_f32_16x16x32_bf16(af[0], bf_, acc[0][nt], 0, 0, 0);
            acc[1][nt] = __builtin_amdgcn_mfma_f32_16x16x32_bf16(af[1], bf_, acc[1][nt], 0, 0, 0);
        }
        __syncthreads();
    }

    // ---- epilogue: acc -> LDS (bf16) ----
    #pragma unroll
    for (int mt = 0; mt < 2; ++mt)
        #pragma unroll
        for (int nt = 0; nt < 14; ++nt)
            #pragma unroll
            for (int r = 0; r < 4; ++r)
                MEM[(wave * 32 + mt * 16 + hi * 4 + r) * SSTRIDE + nt * 16 + lo]
                    = f2bf(acc[mt][nt][r]);
    __syncthreads();

    const int bb = mblk >> 10;                 // batch (blocks never straddle)
    float inv_a = 1.f, corr = 0.f;
    if (actParts) {
        float mean = actParts[bb * 2] / LN_N;
        inv_a = rsqrtf(actParts[bb * 2 + 1] / LN_N - mean * mean + EPS);
        corr = mean * inv_a;
    }
    float mean_r = 0.f, inv_r = 1.f;
    if (resParts) {
        mean_r = resParts[bb * 2] / LN_N;
        inv_r = rsqrtf(resParts[bb * 2 + 1] / LN_N - mean_r * mean_r + EPS);
    }

    // coalesced half-row pass
    const int row = tid >> 1;
    const int octb = (tid & 1) * 14;
    const size_t gm = (size_t)(mblk + row);
    float s = 0.f, s2 = 0.f;
    #pragma unroll
    for (int o8 = 0; o8 < 14; ++o8) {
        const int n0 = (octb + o8) * 8;
        short8 cv = *(const short8*)&MEM[row * SSTRIDE + n0];
        float4 b4a = *(const float4*)(bias + n0);
        float4 b4b = *(const float4*)(bias + n0 + 4);
        float v[8];
        v[0] = bf2f(cv[0]) * inv_a + b4a.x; v[1] = bf2f(cv[1]) * inv_a + b4a.y;
        v[2] = bf2f(cv[2]) * inv_a + b4a.z; v[3] = bf2f(cv[3]) * inv_a + b4a.w;
        v[4] = bf2f(cv[4]) * inv_a + b4b.x; v[5] = bf2f(cv[5]) * inv_a + b4b.y;
        v[6] = bf2f(cv[6]) * inv_a + b4b.z; v[7] = bf2f(cv[7]) * inv_a + b4b.w;
        if (actParts) {
            float4 c4a = *(const float4*)(csW + n0);
            float4 c4b = *(const float4*)(csW + n0 + 4);
            v[0] -= corr * c4a.x; v[1] -= corr * c4a.y;
            v[2] -= corr * c4a.z; v[3] -= corr * c4a.w;
            v[4] -= corr * c4b.x; v[5] -= corr * c4b.y;
            v[6] -= corr * c4b.z; v[7] -= corr * c4b.w;
        }
        if (res) {
            short8 rv = *(const short8*)(res + gm * DPAD + n0);
            #pragma unroll
            for (int j = 0; j < 8; ++j) v[j] += (bf2f(rv[j]) - mean_r) * inv_r;
        }
        if (doRelu)
            #pragma unroll
            for (int j = 0; j < 8; ++j) v[j] = fmaxf(v[j], 0.f);
        #pragma unroll
        for (int j = 0; j < 8; ++j)
            if (n0 + j >= DDIM) v[j] = 0.f;
        if (parts)
            #pragma unroll
            for (int j = 0; j < 8; ++j) { s += v[j]; s2 = fmaf(v[j], v[j], s2); }
        short8 ov;
        #pragma unroll
        for (int j = 0; j < 8; ++j) ov[j] = f2bf(v[j]);
        *(short8*)(out + gm * outStride + n0) = ov;
    }

    if (parts) {
        __shared__ float rs[4], rq[4];
        #pragma unroll
        for (int off = 32; off; off >>= 1) {
            s  += __shfl_down(s, off);
            s2 += __shfl_down(s2, off);
        }
        if (lane == 0) { rs[wave] = s; rq[wave] = s2; }
        __syncthreads();
        if (tid == 0) {
            atomicAdd(&parts[bb * 2],     rs[0] + rs[1] + rs[2] + rs[3]);
            atomicAdd(&parts[bb * 2 + 1], rq[0] + rq[1] + rq[2] + rq[3]);
        }
    }
}

// ---------------- transpose: pt[b][d][s] = p_bf[b][s][d]  (32x32 LDS tiles) ------
__global__ void vt_kernel(const short* __restrict__ p, short* __restrict__ pt)
{
    __shared__ short T[32][33];
    const int b  = blockIdx.z;
    const int s0 = blockIdx.x * 32;
    const int d0 = blockIdx.y * 32;
    const int t  = threadIdx.x;
    const int row = t >> 3, c4 = (t & 7) * 4;
    short4_t v = *(const short4_t*)(p + ((size_t)b * SDIM + s0 + row) * PSTRIDE + d0 + c4);
    #pragma unroll
    for (int j = 0; j < 4; ++j) T[row][c4 + j] = v[j];
    __syncthreads();
    short4_t o;
    #pragma unroll
    for (int j = 0; j < 4; ++j) o[j] = T[c4 + j][row];
    *(short4_t*)(pt + ((size_t)b * DPAD + d0 + row) * SDIM + s0 + c4) = o;
}

// ---------------- fused MFMA flash attention, software-pipelined ----------------
// Per iter kt: stage K[kt+2]/V[kt+1] -> QK[kt+1] -> PV[kt] -> softmax-a[kt+1]
// -> deferred o-rescale -> barrier. All MFMA back-to-back; softmax VALU in shadow.
__global__ __launch_bounds__(256, 2)
void attn_kernel(const short* __restrict__ pbf, const short* __restrict__ pt,
                 short* __restrict__ c, float qscale)
{
    __shared__ short Kbuf[2][7680];   // 32 x 232 (+pad)
    __shared__ short Vbuf[2][6656];   // 208 x 32 (col-xor-swizzled)

    const int bid = blockIdx.x;
    const int wg  = (bid & 7) * 64 + (bid >> 3);   // XCD chunk swizzle
    const int b   = wg >> 3;
    const int q0  = (wg & 7) * 128;

    const int tid  = threadIdx.x;
    const int wave = tid >> 6;
    const int lane = tid & 63;
    const int lo   = lane & 15;
    const int hi   = lane >> 4;

    const short* pb  = pbf + (size_t)b * SDIM * PSTRIDE;
    const short* ptb = pt  + (size_t)b * DPAD * SDIM;

    auto stageK = [&](int kt2, int buf) {
        const short* ks = pb + (size_t)kt2 * 32 * PSTRIDE + lane * 8;
        #pragma unroll
        for (int i = 0; i < 15; ++i)
            gload_lds16(ks + i * 512, &Kbuf[buf][i * 512]);
    };
    auto stageV = [&](int kt2, int buf) {
        #pragma unroll
        for (int i = 0; i < 13; ++i) {
            int e = i * 512 + lane * 8;
            int d = e >> 5;
            int cc = (e & 31) ^ (((d >> 1) & 3) << 3);
            gload_lds16(ptb + (size_t)d * SDIM + kt2 * 32 + cc, &Vbuf[buf][i * 512]);
        }
    };

    // Q fragments (2 qt x 7 ks), pre-scaled into exp2 domain
    short8 qf[2][7];
    #pragma unroll
    for (int qt = 0; qt < 2; ++qt)
        #pragma unroll
        for (int ks = 0; ks < 7; ++ks) {
            short8 q = *(const short8*)(pb + (size_t)(q0 + wave * 32 + qt * 16 + lo) * PSTRIDE
                                        + ks * 32 + hi * 8);
            short8 qs;
            #pragma unroll
            for (int j = 0; j < 8; ++j) qs[j] = f2bf(bf2f(q[j]) * qscale);
            qf[qt][ks] = qs;
        }

    f32x4 o[2][13];
    float m[2], ell[2];
    #pragma unroll
    for (int qt = 0; qt < 2; ++qt) {
        #pragma unroll
        for (int n = 0; n < 13; ++n) o[qt][n] = (f32x4){0.f, 0.f, 0.f, 0.f};
        m[qt] = -1e30f; ell[qt] = 0.f;
    }

    f32x4 sacc[2][2];
    short8 pa_prev[2], pa_next[2];
    float al_s[2]; bool resc[2];

    // softmax part-a on sacc -> m, ell, al_s, resc, pa_next (no o access)
    auto parta = [&]() {
        #pragma unroll
        for (int qt = 0; qt < 2; ++qt) {
            float mx = fmaxf(fmaxf(fmaxf(sacc[qt][0][0], sacc[qt][0][1]),
                                   fmaxf(sacc[qt][0][2], sacc[qt][0][3])),
                             fmaxf(fmaxf(sacc[qt][1][0], sacc[qt][1][1]),
                                   fmaxf(sacc[qt][1][2], sacc[qt][1][3])));
            mx = fmaxf(mx, __shfl_xor(mx, 16));
            mx = fmaxf(mx, __shfl_xor(mx, 32));
            float al = 1.f;
            resc[qt] = __any(mx > m[qt] + 11.5f);     // T13 defer-max (log2 units)
            if (resc[qt]) {
                float mn = fmaxf(m[qt], mx);
                al = exp2f(m[qt] - mn);
                m[qt] = mn;
            }
            al_s[qt] = al;
            float p[2][4]; float rsum = 0.f;
            #pragma unroll
            for (int t = 0; t < 2; ++t)
                #pragma unroll
                for (int r = 0; r < 4; ++r) {
                    p[t][r] = exp2f(sacc[qt][t][r] - m[qt]);
                    rsum += p[t][r];
                }
            rsum += __shfl_xor(rsum, 16);
            rsum += __shfl_xor(rsum, 32);
            ell[qt] = ell[qt] * al + rsum;
            unsigned pk01_0 = cvtpk_bf16(p[0][0], p[0][1]);
            unsigned pk23_0 = cvtpk_bf16(p[0][2], p[0][3]);
            unsigned pk01_1 = cvtpk_bf16(p[1][0], p[1][1]);
            unsigned pk23_1 = cvtpk_bf16(p[1][2], p[1][3]);
            const int srcA = lo + ((hi & 1) * 2) * 16;
            const int srcB = srcA + 16;
            int a0 = __shfl((int)pk01_0, srcA), a1 = __shfl((int)pk01_1, srcA);
            int b0 = __shfl((int)pk23_0, srcA), b1 = __shfl((int)pk23_1, srcA);
            int c0 = __shfl((int)pk01_0, srcB), c1 = __shfl((int)pk01_1, srcB);
            int d0 = __shfl((int)pk23_0, srcB), d1 = __shfl((int)pk23_1, srcB);
            const bool thi = (hi >> 1) != 0;
            union { short8 s; int u[4]; } pu;
            pu.u[0] = thi ? a1 : a0;
            pu.u[1] = thi ? b1 : b0;
            pu.u[2] = thi ? c1 : c0;
            pu.u[3] = thi ? d1 : d0;
            pa_next[qt] = pu.s;
        }
    };

    // prologue: K0,V0,K1 staged; QK(0)+parta(0)
    if (wave == 0) { stageK(0, 0); stageV(0, 0); }
    if (wave == 1) stageK(1, 1);
    __syncthreads();
    {
        #pragma unroll
        for (int qt = 0; qt < 2; ++qt)
            #pragma unroll
            for (int t = 0; t < 2; ++t) sacc[qt][t] = (f32x4){0.f, 0.f, 0.f, 0.f};
        #pragma unroll
        for (int t = 0; t < 2; ++t)
            #pragma unroll
            for (int ks = 0; ks < 7; ++ks) {
                short8 kf = *(const short8*)(&Kbuf[0][(t * 16 + lo) * PSTRIDE + ks * 32 + hi * 8]);
                sacc[0][t] = __builtin_amdgcn_mfma_f32_16x16x32_bf16(kf, qf[0][ks], sacc[0][t], 0, 0, 0);
                sacc[1][t] = __builtin_amdgcn_mfma_f32_16x16x32_bf16(kf, qf[1][ks], sacc[1][t], 0, 0, 0);
            }
        parta();                       // o is zero; al=0 harmless
        pa_prev[0] = pa_next[0];
        pa_prev[1] = pa_next[1];
    }
    __syncthreads();

    for (int kt = 0; kt < 32; ++kt) {
        const int cur = kt & 1;
        // stage ahead: K two tiles, V one tile
        if (kt < 30 && wave == (kt & 3)) stageK(kt + 2, cur);
        if (kt < 31 && wave == ((kt + 2) & 3)) stageV(kt + 1, cur ^ 1);

        const bool have_next = (kt < 31);
        if (have_next) {
            #pragma unroll
            for (int qt = 0; qt < 2; ++qt)
                #pragma unroll
                for (int t = 0; t < 2; ++t) sacc[qt][t] = (f32x4){0.f, 0.f, 0.f, 0.f};
            __builtin_amdgcn_s_setprio(1);
            #pragma unroll
            for (int t = 0; t < 2; ++t)
                #pragma unroll
                for (int ks = 0; ks < 7; ++ks) {
                    short8 kf = *(const short8*)(&Kbuf[cur ^ 1][(t * 16 + lo) * PSTRIDE + ks * 32 + hi * 8]);
                    sacc[0][t] = __builtin_amdgcn_mfma_f32_16x16x32_bf16(kf, qf[0][ks], sacc[0][t], 0, 0, 0);
                    sacc[1][t] = __builtin_amdgcn_mfma_f32_16x16x32_bf16(kf, qf[1][ks], sacc[1][t], 0, 0, 0);
                }
            __builtin_amdgcn_s_setprio(0);
        }

        // PV(kt): uses pa_prev (m-scale of tile kt) — o still in that scale
        __builtin_amdgcn_s_setprio(1);
        #pragma unroll
        for (int n = 0; n < 13; ++n) {
            int d = n * 16 + lo;
            int addr = d * 32 + ((hi * 8) ^ (((d >> 1) & 3) << 3));
            short8 vf = *(const short8*)(&Vbuf[cur][addr]);
            o[0][n] = __builtin_amdgcn_mfma_f32_16x16x32_bf16(pa_prev[0], vf, o[0][n], 0, 0, 0);
            o[1][n] = __builtin_amdgcn_mfma_f32_16x16x32_bf16(pa_prev[1], vf, o[1][n], 0, 0, 0);
        }
        __builtin_amdgcn_s_setprio(0);

        if (have_next) {
            parta();                   // m, ell, pa_next for tile kt+1
            #pragma unroll
            for (int qt = 0; qt < 2; ++qt) {
                if (resc[qt]) {        // deferred o-rescale AFTER PV(kt)
                    float alr[4];
                    #pragma unroll
                    for (int r = 0; r < 4; ++r) alr[r] = __shfl(al_s[qt], hi * 4 + r);
                    #pragma unroll
                    for (int n = 0; n < 13; ++n)
                        #pragma unroll
                        for (int r = 0; r < 4; ++r) o[qt][n][r] *= alr[r];
                }
            }
            pa_prev[0] = pa_next[0];
            pa_prev[1] = pa_next[1];
        }
        __syncthreads();
    }

    // epilogue: O /= ell (ell lives at q=lo lanes; O rows are q=hi*4+r)
    #pragma unroll
    for (int qt = 0; qt < 2; ++qt) {
        float inv_l = 1.f / ell[qt];
        float invr[4];
        #pragma unroll
        for (int r = 0; r < 4; ++r) invr[r] = __shfl(inv_l, hi * 4 + r);
        #pragma unroll
        for (int n = 0; n < 13; ++n) {
            int dcol = n * 16 + lo;
            #pragma unroll
            for (int r = 0; r < 4; ++r) {
                size_t row = (size_t)b * SDIM + q0 + wave * 32 + qt * 16 + hi * 4 + r;
                c[row * DPAD + dcol] = f2bf(o[qt][n][r] * invr[r]);
            }
        }
        #pragma unroll
        for (int r = 0; r < 4; ++r) {
            size_t row = (size_t)b * SDIM + q0 + wave * 32 + qt * 16 + hi * 4 + r;
            c[row * DPAD + 208 + lo] = 0;
        }
    }
}

// ---------------- final: normalize row S-1 only + head ----------------
__global__ void final_kernel(const short* __restrict__ y, const float* __restrict__ parts,
                             const float* __restrict__ Wd, const float* __restrict__ bd,
                             float* __restrict__ out)
{
    const int b = blockIdx.x;
    const float sum = parts[b * 2], sq = parts[b * 2 + 1];
    const float mean = sum / LN_N;
    const float inv  = rsqrtf(sq / LN_N - mean * mean + EPS);
    __shared__ float hrow[DDIM];
    const short* row = y + ((size_t)b * SDIM + SDIM - 1) * DPAD;
    for (int d = threadIdx.x; d < DDIM; d += blockDim.x)
        hrow[d] = (bf2f(row[d]) - mean) * inv;
    __syncthreads();
    if (threadIdx.x < CDIM) {
        float acc = bd[threadIdx.x];
        for (int d = 0; d < DDIM; ++d)
            acc = fmaf(hrow[d], Wd[(size_t)d * CDIM + threadIdx.x], acc);
        out[(size_t)b * CDIM + threadIdx.x] = acc;
    }
}

extern "C" void kernel_launch(void* const* d_in, const int* in_sizes, int n_in,
                              void* d_out, int out_size, void* d_ws, size_t ws_size,
                              hipStream_t stream)
{
    const int*   x     = (const int*)  d_in[0];
    const float* embed = (const float*)d_in[1];
    const float* pos   = (const float*)d_in[2];
    const float* Wp    = (const float*)d_in[3];
    const float* bp    = (const float*)d_in[4];
    const float* Wm    = (const float*)d_in[5];
    const float* bm    = (const float*)d_in[6];
    const float* W1    = (const float*)d_in[7];
    const float* b1    = (const float*)d_in[8];
    const float* W2    = (const float*)d_in[9];
    const float* b2    = (const float*)d_in[10];
    const float* Wd    = (const float*)d_in[11];
    const float* bd    = (const float*)d_in[12];
    float* out = (float*)d_out;

    const size_t HB = (size_t)BDIM * SDIM * DPAD;     // 14,680,064 bf16 elems
    const size_t PB = (size_t)BDIM * SDIM * PSTRIDE;  // p_bf with stride 232

    short* h_bf  = (short*)d_ws;
    short* p_bf  = h_bf  + HB;
    short* pt    = p_bf  + PB;
    short* cb_bf = pt    + HB;
    short* yA    = cb_bf + HB;
    short* yB    = yA    + HB;
    short* WtP   = yB + HB;
    short* WtM   = WtP + DPAD * DPAD;
    short* Wt1   = WtM + DPAD * DPAD;
    short* Wt2   = Wt1 + DPAD * DPAD;
    float* bpP   = (float*)(Wt2 + DPAD * DPAD);
    float* bmP   = bpP + DPAD;
    float* b1P   = bmP + DPAD;
    float* b2P   = b1P + DPAD;
    float* csP   = b2P + DPAD;
    float* cs1   = csP + DPAD;
    float* parts = cs1 + DPAD;                        // 4 x 64 x 2 floats
    const size_t need = (size_t)((char*)(parts + 4 * BDIM * 2) - (char*)d_ws);
    if (ws_size < need) return;

    float* pA1 = parts;
    float* pB1 = parts + BDIM * 2;
    float* pA2 = parts + 2 * BDIM * 2;
    float* pB2 = parts + 3 * BDIM * 2;

    prep_kernel<<<dim3((DPAD * DPAD + 255) / 256), dim3(256), 0, stream>>>(
        Wp, bp, Wm, bm, W1, b1, W2, b2, WtP, WtM, Wt1, Wt2, bpP, bmP, b1P, b2P, csP, cs1);
    embed_kernel<<<dim3(2048), dim3(256), 0, stream>>>(x, embed, pos, h_bf);
    hipMemsetAsync(parts, 0, 4 * BDIM * 2 * sizeof(float), stream);

    const float qscale = 1.44269504f / sqrtf((float)DDIM);
    const dim3 tgrid(SDIM / 32, DPAD / 32, BDIM);

    // stack 1
    gemm_bf<<<dim3(512), dim3(256), 0, stream>>>(h_bf, nullptr, WtP, bpP, nullptr,
                                                 nullptr, nullptr, p_bf, nullptr, 0, PSTRIDE);
    vt_kernel<<<tgrid, dim3(256), 0, stream>>>(p_bf, pt);
    attn_kernel<<<dim3(512), dim3(256), 0, stream>>>(p_bf, pt, cb_bf, qscale);
    gemm_bf<<<dim3(512), dim3(256), 0, stream>>>(cb_bf, nullptr, WtM, bmP, nullptr,
                                                 h_bf, nullptr, yA, pA1, 0, DPAD);
    gemm_bf<<<dim3(512), dim3(256), 0, stream>>>(yA, pA1, Wt1, b1P, cs1,
                                                 nullptr, nullptr, cb_bf, nullptr, 1, DPAD);
    gemm_bf<<<dim3(512), dim3(256), 0, stream>>>(cb_bf, nullptr, Wt2, b2P, nullptr,
                                                 yA, pA1, yB, pB1, 0, DPAD);
    // stack 2
    gemm_bf<<<dim3(512), dim3(256), 0, stream>>>(yB, pB1, WtP, bpP, csP,
                                                 nullptr, nullptr, p_bf, nullptr, 0, PSTRIDE);
    vt_kernel<<<tgrid, dim3(256), 0, stream>>>(p_bf, pt);
    attn_kernel<<<dim3(512), dim3(256), 0, stream>>>(p_bf, pt, cb_bf, qscale);
    gemm_bf<<<dim3(512), dim3(256), 0, stream>>>(cb_bf, nullptr, WtM, bmP, nullptr,
                                                 yB, pB1, h_bf, pA2, 0, DPAD);
    gemm_bf<<<dim3(512), dim3(256), 0, stream>>>(h_bf, pA2, Wt1, b1P, cs1,
                                                 nullptr, nullptr, cb_bf, nullptr, 1, DPAD);
    gemm_bf<<<dim3(512), dim3(256), 0, stream>>>(cb_bf, nullptr, Wt2, b2P, nullptr,
                                                 h_bf, pA2, yA, pB2, 0, DPAD);
    final_kernel<<<dim3(BDIM), dim3(64), 0, stream>>>(yA, pB2, Wd, bd, out);
}

// Round 9
// 433.260 us; speedup vs baseline: 1.2096x; 1.2096x over previous
//
#include <hip/hip_runtime.h>
#include <cstddef>
#include <cstdint>
#include <cmath>

// Problem constants
#define BDIM  64
#define SDIM  1024
#define DDIM  200
#define DPAD  224            // 7 x 32 k-steps, 14 x 16 n-tiles
#define PSTRIDE 232          // global row stride of p_bf (== LDS K stride, bank-friendly)
#define CDIM  31
#define NSTACK 2
#define EPS   1e-5f
#define LN_N  204800.0f      // 1024*200 elements per batch LN plane

typedef __attribute__((ext_vector_type(8))) short short8;
typedef __attribute__((ext_vector_type(4))) short short4_t;
typedef __attribute__((ext_vector_type(4))) float f32x4;

__device__ __forceinline__ short f2bf(float f) {
    union { float f; unsigned u; } v; v.f = f;
    unsigned r = v.u + 0x7FFFu + ((v.u >> 16) & 1u);   // RNE
    return (short)(r >> 16);
}
__device__ __forceinline__ float bf2f(short s) {
    union { unsigned u; float f; } v; v.u = ((unsigned)(unsigned short)s) << 16;
    return v.f;
}
__device__ __forceinline__ unsigned cvtpk_bf16(float a, float b) {
    unsigned r;
    asm volatile("v_cvt_pk_bf16_f32 %0, %1, %2" : "=v"(r) : "v"(a), "v"(b));
    return r;
}
__device__ __forceinline__ void gload_lds16(const short* g, short* l) {
    __builtin_amdgcn_global_load_lds(
        (const __attribute__((address_space(1))) void*)g,
        (__attribute__((address_space(3))) void*)l, 16, 0, 0);
}

// ---------------- prep: padded bf16 transposed weights, biases, colsums --------
__global__ void prep_kernel(const float* __restrict__ Wp, const float* __restrict__ bp,
                            const float* __restrict__ Wm, const float* __restrict__ bm,
                            const float* __restrict__ W1, const float* __restrict__ b1,
                            const float* __restrict__ W2, const float* __restrict__ b2,
                            short* __restrict__ WtP, short* __restrict__ WtM,
                            short* __restrict__ Wt1, short* __restrict__ Wt2,
                            float* __restrict__ bpP, float* __restrict__ bmP,
                            float* __restrict__ b1P, float* __restrict__ b2P,
                            float* __restrict__ csP, float* __restrict__ cs1)
{
    int idx = blockIdx.x * 256 + threadIdx.x;
    if (idx >= DPAD * DPAD) return;
    int n = idx / DPAD, k = idx - n * DPAD;
    bool valid = (n < DDIM) && (k < DDIM);
    WtP[idx] = valid ? f2bf(Wp[(size_t)k * DDIM + n]) : 0;
    Wt1[idx] = valid ? f2bf(W1[(size_t)k * DDIM + n]) : 0;
    Wt2[idx] = valid ? f2bf(W2[(size_t)k * DDIM + n]) : 0;
    float s = 0.f;
    if (valid) {
        #pragma unroll
        for (int blk = 0; blk < 8; ++blk)
            s += Wm[(size_t)(blk * DDIM + k) * DDIM + n];
    }
    WtM[idx] = valid ? f2bf(s) : 0;
    if (idx < DPAD) {
        bpP[idx] = idx < DDIM ? bp[idx] : 0.f;
        bmP[idx] = idx < DDIM ? bm[idx] : 0.f;
        b1P[idx] = idx < DDIM ? b1[idx] : 0.f;
        b2P[idx] = idx < DDIM ? b2[idx] : 0.f;
        float sp = 0.f, s1 = 0.f;
        if (idx < DDIM) {
            for (int kk = 0; kk < DDIM; ++kk) {
                sp += bf2f(f2bf(Wp[(size_t)kk * DDIM + idx]));
                s1 += bf2f(f2bf(W1[(size_t)kk * DDIM + idx]));
            }
        }
        csP[idx] = sp;
        cs1[idx] = s1;
    }
}

// ---------------- h_bf = bf16(embed[x] + pos), zero-padded to 224 ----------------
__global__ void embed_kernel(const int* __restrict__ x, const float* __restrict__ embed,
                             const float* __restrict__ pos, short* __restrict__ h)
{
    const int total = BDIM * SDIM * (DPAD / 4);
    for (int i = blockIdx.x * 256 + threadIdx.x; i < total; i += gridDim.x * 256) {
        const int row = i / (DPAD / 4);
        const int n0  = (i - row * (DPAD / 4)) * 4;
        short4_t o;
        if (n0 >= DDIM) {
            o[0] = o[1] = o[2] = o[3] = 0;
        } else {
            const int s = row & (SDIM - 1);
            const int tok = x[row];
            const float4 e  = *(const float4*)(embed + (size_t)tok * DDIM + n0);
            const float4 p4 = *(const float4*)(pos + (size_t)s * DDIM + n0);
            o[0] = f2bf(e.x + p4.x); o[1] = f2bf(e.y + p4.y);
            o[2] = f2bf(e.z + p4.z); o[3] = f2bf(e.w + p4.w);
        }
        *(short4_t*)(h + (size_t)row * DPAD + n0) = o;
    }
}

// ---------------- bf16 MFMA GEMM: Wt-only LDS dbuf, act direct, fused LN --------
// out[M,224] = LN?(act) @ Wt^T + bias (+ LN?(res)) (+relu) (+stats)
// A=act rows (direct global short8 loads: no cross-wave reuse -> no staging),
// B=Wt rows (LDS, 4x cross-wave reuse). C row=m(hi,r), col=n(lo).
#define WSLICE 7168   // 224*32 shorts per buffer
__global__ __launch_bounds__(256, 3)
void gemm_bf(const short* __restrict__ act, const float* __restrict__ actParts,
             const short* __restrict__ Wt, const float* __restrict__ bias,
             const float* __restrict__ csW,
             const short* __restrict__ res, const float* __restrict__ resParts,
             short* __restrict__ out, float* __restrict__ parts,
             int doRelu, int outStride)
{
    __shared__ short WB[2][WSLICE];   // 28672 B -> 3 blocks/CU

    const int tid  = threadIdx.x;
    const int wave = tid >> 6, lane = tid & 63;
    const int lo   = lane & 15, hi = lane >> 4;
    const int mblk = blockIdx.x * 128;
    const int m0   = mblk + wave * 32;

    // stage Wt k-slice ks (224x32) into WB[buf]; source pre-XOR'd so the
    // swizzled ds_read_b128 below sees chunk hi at (hi ^ ((row>>1)&3))
    auto stage = [&](int ks, int buf) {
        for (int c = wave; c < 14; c += 4) {
            int row = c * 16 + (lane >> 2);
            int kc  = (lane & 3) ^ ((row >> 1) & 3);
            gload_lds16(Wt + (size_t)row * DPAD + ks * 32 + kc * 8,
                        &WB[buf][c * 512 + lane * 8]);
        }
    };

    f32x4 acc[2][14];
    #pragma unroll
    for (int mt = 0; mt < 2; ++mt)
        #pragma unroll
        for (int nt = 0; nt < 14; ++nt) acc[mt][nt] = (f32x4){0.f, 0.f, 0.f, 0.f};

    stage(0, 0);
    __syncthreads();

    #pragma unroll
    for (int ks = 0; ks < 7; ++ks) {
        const int cur = ks & 1;
        if (ks < 6) stage(ks + 1, cur ^ 1);

        short8 af[2];
        #pragma unroll
        for (int mt = 0; mt < 2; ++mt)
            af[mt] = *(const short8*)(act + (size_t)(m0 + mt * 16 + lo) * DPAD
                                      + ks * 32 + hi * 8);
        #pragma unroll
        for (int nt = 0; nt < 14; ++nt) {
            int brow = nt * 16 + lo;
            short8 bf_ = *(const short8*)&WB[cur][brow * 32
                                                  + ((hi * 8) ^ (((brow >> 1) & 3) << 3))];
            acc[0][nt] = __builtin_amdgcn_mfma_f32_16x16x32_bf16(af[0], bf_, acc[0][nt], 0, 0, 0);
            acc[1][nt] = __builtin_amdgcn_mfma_f32_16x16x32_bf16(af[1], bf_, acc[1][nt], 0, 0, 0);
        }
        __syncthreads();
    }

    const int bb = mblk >> 10;                 // batch (blocks never straddle)
    float inv_a = 1.f, corr = 0.f;
    if (actParts) {
        float mean = actParts[bb * 2] / LN_N;
        inv_a = rsqrtf(actParts[bb * 2 + 1] / LN_N - mean * mean + EPS);
        corr = mean * inv_a;
    }
    float mean_r = 0.f, inv_r = 1.f;
    if (resParts) {
        mean_r = resParts[bb * 2] / LN_N;
        inv_r = rsqrtf(resParts[bb * 2 + 1] / LN_N - mean_r * mean_r + EPS);
    }

    float s = 0.f, s2 = 0.f;
    #pragma unroll
    for (int mt = 0; mt < 2; ++mt) {
        #pragma unroll
        for (int nt = 0; nt < 14; ++nt) {
            const int n = nt * 16 + lo;
            const float bn = bias[n];
            const float cw = actParts ? csW[n] : 0.f;
            float v[4];
            #pragma unroll
            for (int r = 0; r < 4; ++r)
                v[r] = acc[mt][nt][r] * inv_a + bn - corr * cw;
            if (res) {
                #pragma unroll
                for (int r = 0; r < 4; ++r) {
                    int m = m0 + mt * 16 + hi * 4 + r;
                    v[r] += (bf2f(res[(size_t)m * DPAD + n]) - mean_r) * inv_r;
                }
            }
            if (doRelu)
                #pragma unroll
                for (int r = 0; r < 4; ++r) v[r] = fmaxf(v[r], 0.f);
            if (n >= DDIM)
                #pragma unroll
                for (int r = 0; r < 4; ++r) v[r] = 0.f;
            if (parts)
                #pragma unroll
                for (int r = 0; r < 4; ++r) { s += v[r]; s2 = fmaf(v[r], v[r], s2); }
            #pragma unroll
            for (int r = 0; r < 4; ++r) {
                int m = m0 + mt * 16 + hi * 4 + r;
                out[(size_t)m * outStride + n] = f2bf(v[r]);
            }
        }
    }

    if (parts) {
        __shared__ float rs[4], rq[4];
        #pragma unroll
        for (int off = 32; off; off >>= 1) {
            s  += __shfl_down(s, off);
            s2 += __shfl_down(s2, off);
        }
        if (lane == 0) { rs[wave] = s; rq[wave] = s2; }
        __syncthreads();
        if (tid == 0) {
            atomicAdd(&parts[bb * 2],     rs[0] + rs[1] + rs[2] + rs[3]);
            atomicAdd(&parts[bb * 2 + 1], rq[0] + rq[1] + rq[2] + rq[3]);
        }
    }
}

// ---------------- transpose: pt[b][d][s] = p_bf[b][s][d]  (32x32 LDS tiles) ------
__global__ void vt_kernel(const short* __restrict__ p, short* __restrict__ pt)
{
    __shared__ short T[32][33];
    const int b  = blockIdx.z;
    const int s0 = blockIdx.x * 32;
    const int d0 = blockIdx.y * 32;
    const int t  = threadIdx.x;
    const int row = t >> 3, c4 = (t & 7) * 4;
    short4_t v = *(const short4_t*)(p + ((size_t)b * SDIM + s0 + row) * PSTRIDE + d0 + c4);
    #pragma unroll
    for (int j = 0; j < 4; ++j) T[row][c4 + j] = v[j];
    __syncthreads();
    short4_t o;
    #pragma unroll
    for (int j = 0; j < 4; ++j) o[j] = T[c4 + j][row];
    *(short4_t*)(pt + ((size_t)b * DPAD + d0 + row) * SDIM + s0 + c4) = o;
}

// ---------------- fused MFMA flash attention (proven round-6/7 version) ---------
// 512 blocks x 4 waves; QBLK=128 (32 q/wave as 2 qt). KVBLK=32, 32 iters.
// K/V double-buffered via global_load_lds (round-robin issuing wave, 1 barrier/iter).
// Swapped QK^T (mfma(K,Q)) -> lane-local softmax; P->A-frag via cvt_pk + shuffles.
__global__ __launch_bounds__(256, 2)
void attn_kernel(const short* __restrict__ pbf, const short* __restrict__ pt,
                 short* __restrict__ c, float qscale)
{
    __shared__ short Kbuf[2][7680];   // 32 x 232 (+pad)
    __shared__ short Vbuf[2][6656];   // 208 x 32 (col-xor-swizzled)

    const int bid = blockIdx.x;
    const int wg  = (bid & 7) * 64 + (bid >> 3);   // XCD chunk swizzle
    const int b   = wg >> 3;
    const int q0  = (wg & 7) * 128;

    const int tid  = threadIdx.x;
    const int wave = tid >> 6;
    const int lane = tid & 63;
    const int lo   = lane & 15;
    const int hi   = lane >> 4;

    const short* pb  = pbf + (size_t)b * SDIM * PSTRIDE;
    const short* ptb = pt  + (size_t)b * DPAD * SDIM;

    auto stage = [&](int kt2, int bufIdx) {
        const short* ks = pb + (size_t)kt2 * 32 * PSTRIDE + lane * 8;
        #pragma unroll
        for (int i = 0; i < 15; ++i)
            gload_lds16(ks + i * 512, &Kbuf[bufIdx][i * 512]);
        #pragma unroll
        for (int i = 0; i < 13; ++i) {
            int e = i * 512 + lane * 8;
            int d = e >> 5;
            int cc = (e & 31) ^ (((d >> 1) & 3) << 3);
            gload_lds16(ptb + (size_t)d * SDIM + kt2 * 32 + cc, &Vbuf[bufIdx][i * 512]);
        }
    };

    short8 qf[2][7];
    #pragma unroll
    for (int qt = 0; qt < 2; ++qt)
        #pragma unroll
        for (int ks = 0; ks < 7; ++ks) {
            short8 q = *(const short8*)(pb + (size_t)(q0 + wave * 32 + qt * 16 + lo) * PSTRIDE
                                        + ks * 32 + hi * 8);
            short8 qs;
            #pragma unroll
            for (int j = 0; j < 8; ++j) qs[j] = f2bf(bf2f(q[j]) * qscale);
            qf[qt][ks] = qs;
        }

    f32x4 o[2][13];
    float m[2], ell[2];
    #pragma unroll
    for (int qt = 0; qt < 2; ++qt) {
        #pragma unroll
        for (int n = 0; n < 13; ++n) o[qt][n] = (f32x4){0.f, 0.f, 0.f, 0.f};
        m[qt] = -1e30f; ell[qt] = 0.f;
    }

    if (wave == 0) stage(0, 0);
    __syncthreads();

    for (int kt = 0; kt < 32; ++kt) {
        const int cur = kt & 1;
        if (kt < 31 && wave == ((kt + 1) & 3)) stage(kt + 1, cur ^ 1);

        f32x4 sacc[2][2];
        #pragma unroll
        for (int qt = 0; qt < 2; ++qt)
            #pragma unroll
            for (int t = 0; t < 2; ++t) sacc[qt][t] = (f32x4){0.f, 0.f, 0.f, 0.f};
        __builtin_amdgcn_s_setprio(1);
        #pragma unroll
        for (int t = 0; t < 2; ++t)
            #pragma unroll
            for (int ks = 0; ks < 7; ++ks) {
                short8 kf = *(const short8*)(&Kbuf[cur][(t * 16 + lo) * PSTRIDE + ks * 32 + hi * 8]);
                sacc[0][t] = __builtin_amdgcn_mfma_f32_16x16x32_bf16(kf, qf[0][ks], sacc[0][t], 0, 0, 0);
                sacc[1][t] = __builtin_amdgcn_mfma_f32_16x16x32_bf16(kf, qf[1][ks], sacc[1][t], 0, 0, 0);
            }
        __builtin_amdgcn_s_setprio(0);

        short8 pa[2];
        #pragma unroll
        for (int qt = 0; qt < 2; ++qt) {
            float mx = fmaxf(fmaxf(fmaxf(sacc[qt][0][0], sacc[qt][0][1]),
                                   fmaxf(sacc[qt][0][2], sacc[qt][0][3])),
                             fmaxf(fmaxf(sacc[qt][1][0], sacc[qt][1][1]),
                                   fmaxf(sacc[qt][1][2], sacc[qt][1][3])));
            mx = fmaxf(mx, __shfl_xor(mx, 16));
            mx = fmaxf(mx, __shfl_xor(mx, 32));
            if (__any(mx > m[qt] + 11.5f)) {          // T13 defer-max (log2 units)
                float mn = fmaxf(m[qt], mx);
                float al = exp2f(m[qt] - mn);
                m[qt] = mn; ell[qt] *= al;
                float alr[4];
                #pragma unroll
                for (int r = 0; r < 4; ++r) alr[r] = __shfl(al, hi * 4 + r);
                #pragma unroll
                for (int n = 0; n < 13; ++n)
                    #pragma unroll
                    for (int r = 0; r < 4; ++r) o[qt][n][r] *= alr[r];
            }
            float p[2][4]; float rsum = 0.f;
            #pragma unroll
            for (int t = 0; t < 2; ++t)
                #pragma unroll
                for (int r = 0; r < 4; ++r) {
                    p[t][r] = exp2f(sacc[qt][t][r] - m[qt]);
                    rsum += p[t][r];
                }
            rsum += __shfl_xor(rsum, 16);
            rsum += __shfl_xor(rsum, 32);
            ell[qt] += rsum;
            unsigned pk01_0 = cvtpk_bf16(p[0][0], p[0][1]);
            unsigned pk23_0 = cvtpk_bf16(p[0][2], p[0][3]);
            unsigned pk01_1 = cvtpk_bf16(p[1][0], p[1][1]);
            unsigned pk23_1 = cvtpk_bf16(p[1][2], p[1][3]);
            const int srcA = lo + ((hi & 1) * 2) * 16;
            const int srcB = srcA + 16;
            int a0 = __shfl((int)pk01_0, srcA), a1 = __shfl((int)pk01_1, srcA);
            int b0 = __shfl((int)pk23_0, srcA), b1 = __shfl((int)pk23_1, srcA);
            int c0 = __shfl((int)pk01_0, srcB), c1 = __shfl((int)pk01_1, srcB);
            int d0 = __shfl((int)pk23_0, srcB), d1 = __shfl((int)pk23_1, srcB);
            const bool thi = (hi >> 1) != 0;
            union { short8 s; int u[4]; } pu;
            pu.u[0] = thi ? a1 : a0;
            pu.u[1] = thi ? b1 : b0;
            pu.u[2] = thi ? c1 : c0;
            pu.u[3] = thi ? d1 : d0;
            pa[qt] = pu.s;
        }

        __builtin_amdgcn_s_setprio(1);
        #pragma unroll
        for (int n = 0; n < 13; ++n) {
            int d = n * 16 + lo;
            int addr = d * 32 + ((hi * 8) ^ (((d >> 1) & 3) << 3));
            short8 vf = *(const short8*)(&Vbuf[cur][addr]);
            o[0][n] = __builtin_amdgcn_mfma_f32_16x16x32_bf16(pa[0], vf, o[0][n], 0, 0, 0);
            o[1][n] = __builtin_amdgcn_mfma_f32_16x16x32_bf16(pa[1], vf, o[1][n], 0, 0, 0);
        }
        __builtin_amdgcn_s_setprio(0);

        __syncthreads();
    }

    #pragma unroll
    for (int qt = 0; qt < 2; ++qt) {
        float inv_l = 1.f / ell[qt];
        float invr[4];
        #pragma unroll
        for (int r = 0; r < 4; ++r) invr[r] = __shfl(inv_l, hi * 4 + r);
        #pragma unroll
        for (int n = 0; n < 13; ++n) {
            int dcol = n * 16 + lo;
            #pragma unroll
            for (int r = 0; r < 4; ++r) {
                size_t row = (size_t)b * SDIM + q0 + wave * 32 + qt * 16 + hi * 4 + r;
                c[row * DPAD + dcol] = f2bf(o[qt][n][r] * invr[r]);
            }
        }
        #pragma unroll
        for (int r = 0; r < 4; ++r) {
            size_t row = (size_t)b * SDIM + q0 + wave * 32 + qt * 16 + hi * 4 + r;
            c[row * DPAD + 208 + lo] = 0;
        }
    }
}

// ---------------- final: normalize row S-1 only + head ----------------
__global__ void final_kernel(const short* __restrict__ y, const float* __restrict__ parts,
                             const float* __restrict__ Wd, const float* __restrict__ bd,
                             float* __restrict__ out)
{
    const int b = blockIdx.x;
    const float sum = parts[b * 2], sq = parts[b * 2 + 1];
    const float mean = sum / LN_N;
    const float inv  = rsqrtf(sq / LN_N - mean * mean + EPS);
    __shared__ float hrow[DDIM];
    const short* row = y + ((size_t)b * SDIM + SDIM - 1) * DPAD;
    for (int d = threadIdx.x; d < DDIM; d += blockDim.x)
        hrow[d] = (bf2f(row[d]) - mean) * inv;
    __syncthreads();
    if (threadIdx.x < CDIM) {
        float acc = bd[threadIdx.x];
        for (int d = 0; d < DDIM; ++d)
            acc = fmaf(hrow[d], Wd[(size_t)d * CDIM + threadIdx.x], acc);
        out[(size_t)b * CDIM + threadIdx.x] = acc;
    }
}

extern "C" void kernel_launch(void* const* d_in, const int* in_sizes, int n_in,
                              void* d_out, int out_size, void* d_ws, size_t ws_size,
                              hipStream_t stream)
{
    const int*   x     = (const int*)  d_in[0];
    const float* embed = (const float*)d_in[1];
    const float* pos   = (const float*)d_in[2];
    const float* Wp    = (const float*)d_in[3];
    const float* bp    = (const float*)d_in[4];
    const float* Wm    = (const float*)d_in[5];
    const float* bm    = (const float*)d_in[6];
    const float* W1    = (const float*)d_in[7];
    const float* b1    = (const float*)d_in[8];
    const float* W2    = (const float*)d_in[9];
    const float* b2    = (const float*)d_in[10];
    const float* Wd    = (const float*)d_in[11];
    const float* bd    = (const float*)d_in[12];
    float* out = (float*)d_out;

    const size_t HB = (size_t)BDIM * SDIM * DPAD;     // 14,680,064 bf16 elems
    const size_t PB = (size_t)BDIM * SDIM * PSTRIDE;  // p_bf with stride 232

    short* h_bf  = (short*)d_ws;
    short* p_bf  = h_bf  + HB;
    short* pt    = p_bf  + PB;
    short* cb_bf = pt    + HB;
    short* yA    = cb_bf + HB;
    short* yB    = yA    + HB;
    short* WtP   = yB + HB;
    short* WtM   = WtP + DPAD * DPAD;
    short* Wt1   = WtM + DPAD * DPAD;
    short* Wt2   = Wt1 + DPAD * DPAD;
    float* bpP   = (float*)(Wt2 + DPAD * DPAD);
    float* bmP   = bpP + DPAD;
    float* b1P   = bmP + DPAD;
    float* b2P   = b1P + DPAD;
    float* csP   = b2P + DPAD;
    float* cs1   = csP + DPAD;
    float* parts = cs1 + DPAD;                        // 4 x 64 x 2 floats
    const size_t need = (size_t)((char*)(parts + 4 * BDIM * 2) - (char*)d_ws);
    if (ws_size < need) return;

    float* pA1 = parts;
    float* pB1 = parts + BDIM * 2;
    float* pA2 = parts + 2 * BDIM * 2;
    float* pB2 = parts + 3 * BDIM * 2;

    prep_kernel<<<dim3((DPAD * DPAD + 255) / 256), dim3(256), 0, stream>>>(
        Wp, bp, Wm, bm, W1, b1, W2, b2, WtP, WtM, Wt1, Wt2, bpP, bmP, b1P, b2P, csP, cs1);
    embed_kernel<<<dim3(2048), dim3(256), 0, stream>>>(x, embed, pos, h_bf);
    hipMemsetAsync(parts, 0, 4 * BDIM * 2 * sizeof(float), stream);

    const float qscale = 1.44269504f / sqrtf((float)DDIM);
    const dim3 tgrid(SDIM / 32, DPAD / 32, BDIM);

    // stack 1
    gemm_bf<<<dim3(512), dim3(256), 0, stream>>>(h_bf, nullptr, WtP, bpP, nullptr,
                                                 nullptr, nullptr, p_bf, nullptr, 0, PSTRIDE);
    vt_kernel<<<tgrid, dim3(256), 0, stream>>>(p_bf, pt);
    attn_kernel<<<dim3(512), dim3(256), 0, stream>>>(p_bf, pt, cb_bf, qscale);
    gemm_bf<<<dim3(512), dim3(256), 0, stream>>>(cb_bf, nullptr, WtM, bmP, nullptr,
                                                 h_bf, nullptr, yA, pA1, 0, DPAD);
    gemm_bf<<<dim3(512), dim3(256), 0, stream>>>(yA, pA1, Wt1, b1P, cs1,
                                                 nullptr, nullptr, cb_bf, nullptr, 1, DPAD);
    gemm_bf<<<dim3(512), dim3(256), 0, stream>>>(cb_bf, nullptr, Wt2, b2P, nullptr,
                                                 yA, pA1, yB, pB1, 0, DPAD);
    // stack 2
    gemm_bf<<<dim3(512), dim3(256), 0, stream>>>(yB, pB1, WtP, bpP, csP,
                                                 nullptr, nullptr, p_bf, nullptr, 0, PSTRIDE);
    vt_kernel<<<tgrid, dim3(256), 0, stream>>>(p_bf, pt);
    attn_kernel<<<dim3(512), dim3(256), 0, stream>>>(p_bf, pt, cb_bf, qscale);
    gemm_bf<<<dim3(512), dim3(256), 0, stream>>>(cb_bf, nullptr, WtM, bmP, nullptr,
                                                 yB, pB1, h_bf, pA2, 0, DPAD);
    gemm_bf<<<dim3(512), dim3(256), 0, stream>>>(h_bf, pA2, Wt1, b1P, cs1,
                                                 nullptr, nullptr, cb_bf, nullptr, 1, DPAD);
    gemm_bf<<<dim3(512), dim3(256), 0, stream>>>(cb_bf, nullptr, Wt2, b2P, nullptr,
                                                 h_bf, pA2, yA, pB2, 0, DPAD);
    final_kernel<<<dim3(BDIM), dim3(64), 0, stream>>>(yA, pB2, Wd, bd, out);
}